// Round 1
// 203.741 us; speedup vs baseline: 1.0061x; 1.0061x over previous
//
#include <hip/hip_runtime.h>

// YOLO loss: preds/targets (N,7,7,30) fp32 -> scalar.
// Memory-bound streaming reduction: 192.7 MB read, roofline ~30 us @ 6.3 TB/s.
//
// R2: kill the __syncthreads vmcnt(0)-drain + block-churn serialization seen
// in R1 (70 us @ ~44% of achievable BW, VALUBusy 7%). Persistent SINGLE-WAVE
// blocks (64 thr), each pipelining 64-cell chunks through a private
// double-buffered LDS pair with a COUNTED s_waitcnt vmcnt(15) (never 0 in the
// main loop) -- the T3/T4 counted-vmcnt pattern. One wave per block => no
// barriers anywhere => the compiler never emits a vmcnt(0) drain. 5 blocks/CU
// (30 KiB LDS each) keep ~75-150 KiB of async loads in flight per CU
// continuously, >> the ~10-25 KiB Little's-law requirement.

#define SGRID 7
#define DDIM 30
#define NCLS 20
#define LAMBDA_NOOBJ 0.5f
#define IOU_EPS 1e-10f

#define CHUNK 64                   // cells per chunk (one wave stages+computes)
#define THREADS 64                 // one wave per block
#define NF4P (CHUNK * DDIM / 4)    // 480 float4 per tensor per chunk
#define NF4 (2 * NF4P)             // 960 float4 per chunk (preds ++ targets)
#define PASSES (NF4 / THREADS)     // 15 -- exact; also the vmcnt count
#define GRIDB 1280                 // 5 blocks/CU * 256 CU (30 KiB LDS -> 5 resident)

static_assert(NF4 % THREADS == 0, "stage passes must be exact for counted vmcnt");

// Async 16B global->LDS copy: LDS dest is wave-uniform base + lane*16 (our
// linear i = tid + k*64 mapping satisfies this); the GLOBAL source address is
// per-lane, so a per-lane preds-vs-targets pointer select is legal.
#define GLOAD_LDS16(gp, lp)                                        \
    __builtin_amdgcn_global_load_lds(                              \
        (const __attribute__((address_space(1))) void*)(gp),       \
        (__attribute__((address_space(3))) void*)(lp), 16, 0, 0)

__device__ __forceinline__ void stage_chunk(const float* __restrict__ preds,
                                            const float* __restrict__ targets,
                                            float* lb, int ci, int tid) {
    const long long base = (long long)ci * (CHUNK * DDIM);
    const float4* gp = (const float4*)(preds + base);
    const float4* gt = (const float4*)(targets + base);
#pragma unroll
    for (int k = 0; k < PASSES; ++k) {
        const int i = tid + k * THREADS;
        // Per-lane source select (only k==7 actually mixes; others fold).
        const float4* src = (i < NF4P) ? (gp + i) : (gt + (i - NF4P));
        GLOAD_LDS16(src, lb + i * 4);
    }
}

__device__ __forceinline__ float cell_loss(const float* pv, const float* tv) {
    float loss = 0.0f;

    // IoU per box (center format).
    float iou0, iou1;
#pragma unroll
    for (int b = 0; b < 2; ++b) {
        const float x1 = pv[b * 5 + 0], y1 = pv[b * 5 + 1];
        const float w1 = pv[b * 5 + 2], h1 = pv[b * 5 + 3];
        const float x2 = tv[b * 5 + 0], y2 = tv[b * 5 + 1];
        const float w2 = tv[b * 5 + 2], h2 = tv[b * 5 + 3];
        float iw = fminf(x1 + 0.5f * w1, x2 + 0.5f * w2) -
                   fmaxf(x1 - 0.5f * w1, x2 - 0.5f * w2);
        iw = fmaxf(iw, 0.0f);
        float ih = fminf(y1 + 0.5f * h1, y2 + 0.5f * h2) -
                   fmaxf(y1 - 0.5f * h1, y2 - 0.5f * h2);
        ih = fmaxf(ih, 0.0f);
        const float inter = iw * ih;
        const float uni = w1 * h1 + w2 * h2 - inter;
        const float iou = inter / (uni + IOU_EPS);
        if (b == 0) iou0 = iou; else iou1 = iou;
    }

    // argmax ties -> first index (box 0).
    const bool sel1 = iou1 > iou0;

    // coord loss (selected box x,y), gated by has_obj = targets[...,4] > 0.
    {
        const float px = sel1 ? pv[5] : pv[0];
        const float py = sel1 ? pv[6] : pv[1];
        const float tx = sel1 ? tv[5] : tv[0];
        const float ty = sel1 ? tv[6] : tv[1];
        const float dx = px - tx, dy = py - ty;
        if (tv[4] > 0.0f) loss += dx * dx + dy * dy;
    }

    // class SSE + running argmax of target class (ties -> first);
    // track pc_gt by value to avoid dynamic register indexing.
    float gt_val = tv[10];
    float pc_gt = pv[10];
#pragma unroll
    for (int j = 0; j < NCLS; ++j) {
        const float pc = pv[10 + j], tc = tv[10 + j];
        const float d = pc - tc;
        loss += d * d;
        const bool gm = tc > gt_val;
        gt_val = gm ? tc : gt_val;
        pc_gt = gm ? pc : pc_gt;
    }

    // conf loss: w_b * (iou_b * pc_gt - iou_b)^2 = w_b * iou_b^2 * (pc_gt-1)^2
    const float c = pc_gt - 1.0f;
    const float d0 = iou0 * c, d1 = iou1 * c;
    const float w0 = sel1 ? LAMBDA_NOOBJ : 1.0f;
    const float w1 = sel1 ? 1.0f : LAMBDA_NOOBJ;
    loss += w0 * d0 * d0 + w1 * d1 * d1;
    return loss;
}

__global__ __launch_bounds__(THREADS) void yolo_loss_main(
    const float* __restrict__ preds, const float* __restrict__ targets,
    float* __restrict__ partials, int n_cells) {
    // Double-buffered chunk staging: 2 * 960 float4 = 30720 B -> 5 blocks/CU.
    __shared__ float buf[2][NF4 * 4];

    const int tid = threadIdx.x;
    const int bid = blockIdx.x;
    const int nfull = n_cells / CHUNK;

    float loss = 0.0f;

    if (bid < nfull) {
        // Prologue: stage this block's first chunk.
        stage_chunk(preds, targets, buf[0], bid, tid);
        int cur = 0;
        for (int ci = bid; ci < nfull; ci += GRIDB) {
            const int nx = ci + GRIDB;
            if (nx < nfull) {
                // Issue next chunk's 15 loads, then wait for the PREVIOUS 15
                // only (counted vmcnt) -- next chunk stays in flight under
                // this chunk's compute.
                stage_chunk(preds, targets, buf[cur ^ 1], nx, tid);
                asm volatile("s_waitcnt vmcnt(15)" ::: "memory");
            } else {
                asm volatile("s_waitcnt vmcnt(0)" ::: "memory");
            }
            // Single wave: no barrier needed -- this wave staged everything it
            // reads, and program order guarantees its iter-i ds_reads complete
            // before iter-(i+1) global_load_lds writes can land.
            const float* lp = buf[cur];
            float pv[DDIM], tv[DDIM];
            {
                const float2* p2 = (const float2*)(lp + tid * DDIM);           // 8B-aligned
                const float2* t2 = (const float2*)(lp + NF4P * 4 + tid * DDIM);
#pragma unroll
                for (int i = 0; i < DDIM / 2; ++i) {
                    ((float2*)pv)[i] = p2[i];
                    ((float2*)tv)[i] = t2[i];
                }
            }
            loss += cell_loss(pv, tv);
            cur ^= 1;
        }
    }

    // Ragged tail (n_cells % CHUNK, zero for the bench shape): block 0 loads
    // the leftover cells directly from global (<= 63 cells, negligible).
    const int tail0 = nfull * CHUNK;
    if (bid == 0 && tail0 + tid < n_cells) {
        const long long cb = (long long)(tail0 + tid) * DDIM;
        float pv[DDIM], tv[DDIM];
        const float2* p2 = (const float2*)(preds + cb);   // 120B stride -> 8B-aligned
        const float2* t2 = (const float2*)(targets + cb);
#pragma unroll
        for (int i = 0; i < DDIM / 2; ++i) {
            ((float2*)pv)[i] = p2[i];
            ((float2*)tv)[i] = t2[i];
        }
        loss += cell_loss(pv, tv);
    }

    // Wave-level reduction (block == one wave), one store per block.
#pragma unroll
    for (int off = 32; off > 0; off >>= 1) loss += __shfl_down(loss, off, 64);
    if (tid == 0) partials[bid] = loss;
}

#define RTHREADS 1024
__global__ __launch_bounds__(RTHREADS) void yolo_loss_reduce(
    const float* __restrict__ partials, int n, float inv_n,
    float* __restrict__ out) {
    __shared__ float red[RTHREADS / 64];
    float v = 0.0f;
    for (int i = threadIdx.x; i < n; i += RTHREADS) v += partials[i];
#pragma unroll
    for (int off = 32; off > 0; off >>= 1) v += __shfl_down(v, off, 64);
    if ((threadIdx.x & 63) == 0) red[threadIdx.x >> 6] = v;
    __syncthreads();
    if (threadIdx.x == 0) {
        float s = 0.0f;
#pragma unroll
        for (int w = 0; w < RTHREADS / 64; ++w) s += red[w];
        out[0] = s * inv_n;
    }
}

extern "C" void kernel_launch(void* const* d_in, const int* in_sizes, int n_in,
                              void* d_out, int out_size, void* d_ws, size_t ws_size,
                              hipStream_t stream) {
    const float* preds = (const float*)d_in[0];
    const float* targets = (const float*)d_in[1];
    float* out = (float*)d_out;

    const int total = in_sizes[0];                        // N*S*S*D elements
    const int n_cells = total / DDIM;                     // N*S*S
    const int N = total / (SGRID * SGRID * DDIM);         // 16384

    float* partials = (float*)d_ws;  // GRIDB floats; every block writes once

    yolo_loss_main<<<GRIDB, THREADS, 0, stream>>>(preds, targets, partials, n_cells);
    yolo_loss_reduce<<<1, RTHREADS, 0, stream>>>(partials, GRIDB, 1.0f / (float)N, out);
}